// Round 1
// baseline (3774.572 us; speedup 1.0000x reference)
//
#include <hip/hip_runtime.h>
#include <math.h>

#define NN 3072
#define FF 256
#define CAPE (1<<18)

struct Scal {
  int nnzS, nnz2, nzero;
  int lo, hi; float frac;
  int rank_rem; unsigned prefix_hi; int below_hi;
  unsigned vlo; int c_le; unsigned minabove;
  float cut;
};

__device__ __forceinline__ float sigm(float x){ return 1.0f/(1.0f+expf(-x)); }

// ---------------- CSR build ----------------
__global__ __launch_bounds__(256) void k_count_dense(const float* __restrict__ A, int* __restrict__ rowcnt){
  int i=blockIdx.x, t=threadIdx.x;
  int c=0;
  for(int j=t;j<NN;j+=256){ float a=A[(size_t)i*NN+j]; if(a!=0.0f||j==i) c++; }
  __shared__ int s[256]; s[t]=c; __syncthreads();
  for(int o=128;o;o>>=1){ if(t<o) s[t]+=s[t+o]; __syncthreads(); }
  if(t==0) rowcnt[i]=s[0];
}

__global__ __launch_bounds__(1024) void k_scan(const int* __restrict__ cnt, int* __restrict__ rp, int* __restrict__ total){
  int t=threadIdx.x;
  int a0=cnt[t*3+0], a1=cnt[t*3+1], a2=cnt[t*3+2];
  int loc=a0+a1+a2;
  __shared__ int s[1024];
  s[t]=loc; __syncthreads();
  for(int o=1;o<1024;o<<=1){ int v=(t>=o)?s[t-o]:0; __syncthreads(); s[t]+=v; __syncthreads(); }
  int excl=s[t]-loc;
  rp[t*3+0]=excl; rp[t*3+1]=excl+a0; rp[t*3+2]=excl+a0+a1;
  if(t==1023){ rp[NN]=s[t]; *total=s[t]; }
}

// structure = (A!=0) | diag.  acval: from dense ACd (level 0) or (a+I)/(Di*Dj) (levels>=1)
__global__ __launch_bounds__(256) void k_fill_dense(const float* __restrict__ A, const float* __restrict__ ACd, const float* __restrict__ D,
    const int* __restrict__ rp, int* __restrict__ cols, float* __restrict__ aval, float* __restrict__ acval){
  int i=blockIdx.x, t=threadIdx.x;
  const int CH=NN/256;
  int j0=t*CH; int c=0;
  for(int u=0;u<CH;u++){ int j=j0+u; float a=A[(size_t)i*NN+j]; if(a!=0.0f||j==i) c++; }
  __shared__ int s[256]; s[t]=c; __syncthreads();
  for(int o=1;o<256;o<<=1){ int v=(t>=o)?s[t-o]:0; __syncthreads(); s[t]+=v; __syncthreads(); }
  int pos=rp[i]+s[t]-c;
  float Di = D?D[i]:0.0f;
  for(int u=0;u<CH;u++){ int j=j0+u; float a=A[(size_t)i*NN+j];
    if(a!=0.0f||j==i){
      if(pos<CAPE){
        cols[pos]=j; aval[pos]=a;
        acval[pos]= ACd? ACd[(size_t)i*NN+j] : (a+(j==i?1.0f:0.0f))/(Di*D[j]);
      }
      pos++;
    }
  }
}

// ---------------- dense GEMM (f32, 64x64 tile) ----------------
__global__ __launch_bounds__(256) void k_gemm(const float* __restrict__ A, const float* __restrict__ B, float* __restrict__ C,
                                              int M, int K, int Nc){
  __shared__ float As[16][68];
  __shared__ float Bs[16][68];
  int tid=threadIdx.x;
  int tx=tid&15, ty=tid>>4;
  int bm=blockIdx.y*64, bn=blockIdx.x*64;
  int lm=tid>>2, lk=(tid&3)*4;
  int kr=tid>>4, nf=(tid&15)*4;
  float acc[4][4]={};
  for(int k0=0;k0<K;k0+=16){
    float4 a4=*(const float4*)(A+(size_t)(bm+lm)*K+k0+lk);
    As[lk+0][lm]=a4.x; As[lk+1][lm]=a4.y; As[lk+2][lm]=a4.z; As[lk+3][lm]=a4.w;
    float4 b4=*(const float4*)(B+(size_t)(k0+kr)*Nc+bn+nf);
    *(float4*)&Bs[kr][nf]=b4;
    __syncthreads();
#pragma unroll
    for(int kk=0;kk<16;kk++){
      float4 av=*(const float4*)&As[kk][ty*4];
      float4 bv=*(const float4*)&Bs[kk][tx*4];
      float am[4]={av.x,av.y,av.z,av.w};
      float bb[4]={bv.x,bv.y,bv.z,bv.w};
#pragma unroll
      for(int i2=0;i2<4;i2++)
#pragma unroll
        for(int j2=0;j2<4;j2++) acc[i2][j2]+=am[i2]*bb[j2];
    }
    __syncthreads();
  }
  for(int i2=0;i2<4;i2++){
    float4 o=make_float4(acc[i2][0],acc[i2][1],acc[i2][2],acc[i2][3]);
    *(float4*)(C+(size_t)(bm+ty*4+i2)*Nc+bn+tx*4)=o;
  }
}

__global__ __launch_bounds__(256) void k_gemm16(const float* __restrict__ X, const float* __restrict__ W, float* __restrict__ T){
  int idx=blockIdx.x*256+threadIdx.x;
  if(idx>=NN*16) return;
  int i=idx>>4, o=idx&15;
  float s=0.f;
  for(int kk=0;kk<FF;kk++) s+=X[(size_t)i*FF+kk]*W[kk*16+o];
  T[idx]=s;
}

// ---------------- SpMM (wave per row) ----------------
// act: 0 relu, 1 elu; residual optional; fused l2norm; bias added before act
__global__ __launch_bounds__(256) void k_spmm_gcn(const int* __restrict__ rp, const int* __restrict__ cols, const float* __restrict__ vals,
    const float* __restrict__ X, const float* __restrict__ bias, const float* __restrict__ resid, float* __restrict__ out, int act){
  int wid=blockIdx.x*4+(threadIdx.x>>6);
  int lane=threadIdx.x&63;
  if(wid>=NN) return;
  int e0=rp[wid], e1=rp[wid+1];
  float4 acc=make_float4(0,0,0,0);
  for(int e=e0;e<e1;e++){
    float v=vals[e]; int c=cols[e];
    float4 xv=*(const float4*)(X+(size_t)c*FF+lane*4);
    acc.x+=v*xv.x; acc.y+=v*xv.y; acc.z+=v*xv.z; acc.w+=v*xv.w;
  }
  float4 bv=*(const float4*)(bias+lane*4);
  acc.x+=bv.x; acc.y+=bv.y; acc.z+=bv.z; acc.w+=bv.w;
  if(act==0){
    acc.x=fmaxf(acc.x,0.f); acc.y=fmaxf(acc.y,0.f); acc.z=fmaxf(acc.z,0.f); acc.w=fmaxf(acc.w,0.f);
  } else {
    acc.x=acc.x>0.f?acc.x:expm1f(acc.x); acc.y=acc.y>0.f?acc.y:expm1f(acc.y);
    acc.z=acc.z>0.f?acc.z:expm1f(acc.z); acc.w=acc.w>0.f?acc.w:expm1f(acc.w);
  }
  if(resid){
    float4 r=*(const float4*)(resid+(size_t)wid*FF+lane*4);
    acc.x+=r.x; acc.y+=r.y; acc.z+=r.z; acc.w+=r.w;
  }
  float ss=acc.x*acc.x+acc.y*acc.y+acc.z*acc.z+acc.w*acc.w;
  for(int o=32;o;o>>=1) ss+=__shfl_xor(ss,o);
  float nrm=fmaxf(sqrtf(ss),1e-12f);
  float4 o4=make_float4(acc.x/nrm,acc.y/nrm,acc.z/nrm,acc.w/nrm);
  *(float4*)(out+(size_t)wid*FF+lane*4)=o4;
}

__global__ __launch_bounds__(256) void k_spmm_plain(const int* __restrict__ rp, const int* __restrict__ cols, const float* __restrict__ vals,
    const float* __restrict__ X, float* __restrict__ out){
  int wid=blockIdx.x*4+(threadIdx.x>>6);
  int lane=threadIdx.x&63;
  if(wid>=NN) return;
  int e0=rp[wid], e1=rp[wid+1];
  float4 acc=make_float4(0,0,0,0);
  for(int e=e0;e<e1;e++){
    if(e>=CAPE) break;
    float v=vals[e]; int c=cols[e];
    float4 xv=*(const float4*)(X+(size_t)c*FF+lane*4);
    acc.x+=v*xv.x; acc.y+=v*xv.y; acc.z+=v*xv.z; acc.w+=v*xv.w;
  }
  *(float4*)(out+(size_t)wid*FF+lane*4)=acc;
}

// ---------------- edge score ----------------
__global__ __launch_bounds__(64) void k_edge(const float* __restrict__ X, const float* __restrict__ fw, const float* __restrict__ fb,
    const float* __restrict__ av, float* __restrict__ s1, float* __restrict__ s2){
  int i=blockIdx.x, l=threadIdx.x;
  __shared__ float xr[FF];
  *(float4*)&xr[l*4]=*(const float4*)(X+(size_t)i*FF+l*4);
  __syncthreads();
  float h=fb[l];
  for(int kk=0;kk<FF;kk++) h+=xr[kk]*fw[kk*64+l];
  float p1=h*av[l], p2=h*av[64+l];
  for(int o=32;o;o>>=1){ p1+=__shfl_xor(p1,o); p2+=__shfl_xor(p2,o); }
  if(l==0){ s1[i]=p1; s2[i]=p2; }
}

__global__ void k_snz(Scal* sc){ sc->nzero=0; }

__global__ __launch_bounds__(256) void k_att_fill(const int* __restrict__ rp, const int* __restrict__ cols,
    const float* __restrict__ s1, const float* __restrict__ s2, float* __restrict__ attD, float* __restrict__ cand, Scal* sc){
  int i=blockIdx.x;
  float s1i=s1[i], s2i=s2[i];
  int e1=rp[i+1];
  for(int e=rp[i]+threadIdx.x; e<e1; e+=256){
    int j=cols[e];
    float v;
    if(j==i) v=1.0f;
    else v=0.5f*(sigm(s1i+s2[j])+sigm(s1[j]+s2i));
    attD[(size_t)i*NN+j]=v;
    if(e<CAPE) cand[e]=v;
    if(!(v>0.f)) atomicAdd(&sc->nzero,1);
  }
}

// ---------------- percentile (exact radix select, 16+16 bits) ----------------
__global__ void k_prep(Scal* sc){
  int np=sc->nnzS - sc->nzero;
  float idx=(float)(np-1)*(30.0f/100.0f);
  float fl=floorf(idx), ce=ceilf(idx);
  sc->lo=(int)fl; sc->hi=(int)ce; sc->frac=idx-fl;
  sc->rank_rem=sc->lo;
  sc->minabove=0xFFFFFFFFu;
}

__global__ __launch_bounds__(256) void k_hist(const float* __restrict__ cand, const Scal* __restrict__ sc, unsigned* __restrict__ bins, int phase){
  int n=sc->nnzS; if(n>CAPE) n=CAPE;
  int stride=gridDim.x*256;
  for(int e=blockIdx.x*256+threadIdx.x; e<n; e+=stride){
    float v=cand[e];
    if(!(v>0.f)) continue;
    unsigned b=__float_as_uint(v);
    if(phase==0) atomicAdd(&bins[b>>16],1u);
    else if((b>>16)==sc->prefix_hi) atomicAdd(&bins[b&0xFFFFu],1u);
  }
}

__global__ __launch_bounds__(256) void k_pick(const unsigned* __restrict__ bins, Scal* sc, int phase){
  __shared__ unsigned part[256];
  __shared__ int selbin; __shared__ unsigned below_sel;
  int t=threadIdx.x;
  unsigned sum=0;
  for(int b=t*256;b<t*256+256;b++) sum+=bins[b];
  part[t]=sum; __syncthreads();
  if(t==0){ unsigned run=0; for(int u=0;u<256;u++){ unsigned v=part[u]; part[u]=run; run+=v; } }
  __syncthreads();
  int r=sc->rank_rem;
  unsigned excl=part[t];
  if((unsigned)r>=excl && (unsigned)r<excl+sum){
    unsigned run=excl;
    for(int b=t*256;b<t*256+256;b++){
      unsigned c=bins[b];
      if((unsigned)r<run+c){ selbin=b; below_sel=run; break; }
      run+=c;
    }
  }
  __syncthreads();
  if(t==0){
    if(phase==0){ sc->prefix_hi=(unsigned)selbin; sc->below_hi=(int)below_sel; sc->rank_rem=r-(int)below_sel; }
    else{
      unsigned mult=bins[selbin];
      sc->vlo=(sc->prefix_hi<<16)|(unsigned)selbin;
      sc->c_le=sc->below_hi+(int)below_sel+(int)mult;
    }
  }
}

__global__ __launch_bounds__(256) void k_minabove(const float* __restrict__ cand, Scal* sc){
  int n=sc->nnzS; if(n>CAPE) n=CAPE;
  unsigned vlo=sc->vlo;
  int stride=gridDim.x*256;
  for(int e=blockIdx.x*256+threadIdx.x; e<n; e+=stride){
    float v=cand[e];
    if(!(v>0.f)) continue;
    unsigned b=__float_as_uint(v);
    if(b>vlo) atomicMin(&sc->minabove,b);
  }
}

__global__ void k_cut(Scal* sc){
  float slo=__uint_as_float(sc->vlo);
  float shi;
  if(sc->hi==sc->lo) shi=slo;
  else if(sc->c_le>sc->hi) shi=slo;
  else shi=__uint_as_float(sc->minabove);
  sc->cut=slo*(1.0f-sc->frac)+shi*sc->frac;
}

// ---------------- post-cut CSR ----------------
__global__ __launch_bounds__(256) void k_pc_count(const int* __restrict__ rp, const float* __restrict__ cand, const Scal* __restrict__ sc,
    int* __restrict__ rowcnt, float* __restrict__ cntf){
  int wid=blockIdx.x*4+(threadIdx.x>>6);
  int lane=threadIdx.x&63;
  if(wid>=NN) return;
  int e0=rp[wid], e1=rp[wid+1];
  float cut=sc->cut;
  int c=0;
  for(int e=e0+lane;e<e1;e+=64){ if(e<CAPE && cand[e]>=cut) c++; }
  for(int o=32;o;o>>=1) c+=__shfl_xor(c,o);
  if(lane==0){ rowcnt[wid]=c; cntf[wid]=(float)c; }
}

__global__ __launch_bounds__(256) void k_pc_fill(const int* __restrict__ rp, const int* __restrict__ cols, const float* __restrict__ cand,
    const Scal* __restrict__ sc, const int* __restrict__ rp2, int* __restrict__ rows2, int* __restrict__ cols2, float* __restrict__ pval,
    const float* __restrict__ cntf){
  int wid=blockIdx.x*4+(threadIdx.x>>6);
  int lane=threadIdx.x&63;
  if(wid>=NN) return;
  int e0=rp[wid], e1=rp[wid+1];
  float cut=sc->cut, cf=cntf[wid];
  int base=rp2[wid];
  for(int eb=e0;eb<e1;eb+=64){
    int e=eb+lane;
    bool p=(e<e1)&&(e<CAPE)&&(cand[e]>=cut);
    unsigned long long m=__ballot(p);
    if(p){
      int pos=base+__popcll(m&((1ull<<lane)-1ull));
      if(pos<CAPE){ rows2[pos]=wid; cols2[pos]=cols[e]; pval[pos]=cand[e]/cf; }
    }
    base+=__popcll(m);
  }
}

// ---------------- connected components ----------------
__global__ __launch_bounds__(256) void k_lab_init(int* lab){
  int i=blockIdx.x*256+threadIdx.x; if(i<NN) lab[i]=i;
}
__global__ __launch_bounds__(256) void k_relax(const int* __restrict__ rows2, const int* __restrict__ cols2, const Scal* __restrict__ sc, int* lab){
  int e=blockIdx.x*256+threadIdx.x;
  int n2=sc->nnz2; if(n2>CAPE) n2=CAPE;
  if(e>=n2) return;
  int i=rows2[e], j=cols2[e];
  if(i==j) return;
  int li=lab[i], lj=lab[j];
  if(lj<li) atomicMin(&lab[i],lj);
  else if(li<lj) atomicMin(&lab[j],li);
}
__global__ __launch_bounds__(256) void k_jump(const int* __restrict__ lab, int* __restrict__ nxt){
  int i=blockIdx.x*256+threadIdx.x; if(i<NN) nxt[i]=lab[lab[i]];
}
__global__ __launch_bounds__(256) void k_labfin(const int* __restrict__ lab, int* __restrict__ labsv, int* __restrict__ clc){
  int i=blockIdx.x*256+threadIdx.x;
  if(i<NN){ int l=lab[i]; labsv[i]=l; atomicAdd(&clc[l],1); }
}

// ---------------- pooling ----------------
__global__ __launch_bounds__(256) void k_a2(const int* __restrict__ rp, const int* __restrict__ cols, const float* __restrict__ aval,
    const int* __restrict__ labsv, float* __restrict__ dense){
  int i=blockIdx.x;
  int li=labsv[i];
  int e1=rp[i+1];
  for(int e=rp[i]+threadIdx.x;e<e1;e+=256){
    if(e>=CAPE) break;
    float a=aval[e];
    if(a!=0.f){ int lj=labsv[cols[e]]; atomicAdd(&dense[(size_t)li*NN+lj],a); }
  }
}

__global__ __launch_bounds__(256) void k_rowsumD(const float* __restrict__ dense, float* __restrict__ D){
  int i=blockIdx.x, t=threadIdx.x;
  float s=0;
  for(int j=t;j<NN;j+=256) s+=dense[(size_t)i*NN+j];
  __shared__ float r[256]; r[t]=s; __syncthreads();
  for(int o=128;o;o>>=1){ if(t<o) r[t]+=r[t+o]; __syncthreads(); }
  if(t==0) D[i]=sqrtf(r[0]+1.0f);
}

__global__ __launch_bounds__(256) void k_x2norm(const float* __restrict__ y, const int* __restrict__ labsv, const int* __restrict__ clc,
    float* __restrict__ out){
  int c=blockIdx.x, t=threadIdx.x;
  if(clc[c]==0){ out[(size_t)c*FF+t]=0.f; return; }
  __shared__ int ls[NN];
  for(int j=t;j<NN;j+=256) ls[j]=labsv[j];
  __syncthreads();
  float acc=0.f;
  for(int j=c;j<NN;j++){ if(ls[j]==c) acc+=y[(size_t)j*FF+t]; }
  __shared__ float red[256];
  red[t]=acc*acc; __syncthreads();
  for(int o=128;o;o>>=1){ if(t<o) red[t]+=red[t+o]; __syncthreads(); }
  float nrm=fmaxf(sqrtf(red[0]),1e-12f);
  out[(size_t)c*FF+t]=acc/nrm;
}

// ---------------- decode ----------------
__global__ __launch_bounds__(256) void k_gather(const float* __restrict__ X, const int* __restrict__ labs, const float* __restrict__ xsk,
    float* __restrict__ xcat){
  int idx=blockIdx.x*256+threadIdx.x;
  if(idx>=NN*128) return;
  int j=idx>>7, f4=idx&127;
  float4 v;
  if(f4<64) v=*(const float4*)(X+(size_t)labs[j]*FF+f4*4);
  else v=*(const float4*)(xsk+(size_t)j*FF+(size_t)(f4-64)*4);
  *(float4*)(xcat+(size_t)j*512+(size_t)f4*4)=v;
}

__global__ __launch_bounds__(256) void k_final(const int* __restrict__ rp, const int* __restrict__ cols, const float* __restrict__ vals,
    const float* __restrict__ T, const float* __restrict__ bias, float* __restrict__ logp){
  int i=blockIdx.x*256+threadIdx.x;
  if(i>=NN) return;
  float o[16];
#pragma unroll
  for(int f=0;f<16;f++) o[f]=bias[f];
  int e1=rp[i+1];
  for(int e=rp[i];e<e1;e++){
    float v=vals[e]; const float* tr=T+(size_t)cols[e]*16;
#pragma unroll
    for(int f=0;f<16;f++) o[f]+=v*tr[f];
  }
  float m=o[0];
#pragma unroll
  for(int f=1;f<16;f++) m=fmaxf(m,o[f]);
  float ssum=0.f;
#pragma unroll
  for(int f=0;f<16;f++) ssum+=expf(o[f]-m);
  float lse=logf(ssum);
#pragma unroll
  for(int f=0;f<16;f++) logp[(size_t)i*16+f]=o[f]-m-lse;
}

__global__ __launch_bounds__(256) void k_cfill(const int* __restrict__ labsv, float* __restrict__ CsB){
  int idx=blockIdx.x*256+threadIdx.x;
  if(idx>=3*NN) return;
  int l=idx/NN, j=idx-l*NN;
  int c=labsv[l*NN+j];
  CsB[(size_t)l*NN*NN+(size_t)c*NN+j]=1.0f;
}

// ================= host =================
extern "C" void kernel_launch(void* const* d_in, const int* in_sizes, int n_in,
                              void* d_out, int out_size, void* d_ws, size_t ws_size,
                              hipStream_t stream) {
  (void)in_sizes; (void)n_in; (void)out_size; (void)ws_size;
  const float* x_in =(const float*)d_in[0];
  const float* adjC =(const float*)d_in[1];
  const float* adj  =(const float*)d_in[2];
  const float* encW0=(const float*)d_in[3];
  const float* encb0=(const float*)d_in[4];
  const float* encW =(const float*)d_in[5];
  const float* encb =(const float*)d_in[6];
  const float* fcW  =(const float*)d_in[7];
  const float* fcb  =(const float*)d_in[8];
  const float* aW   =(const float*)d_in[9];
  const float* decW =(const float*)d_in[10];
  const float* decb =(const float*)d_in[11];
  const float* decWo=(const float*)d_in[12];
  const float* decbo=(const float*)d_in[13];
  float* out=(float*)d_out;

  float* logp=out;
  float* CsB = out + (size_t)NN*16;
  float* attB= CsB + 3ull*NN*NN;
  // d_out scratch (free until the final Cs memset+fill):
  float* dA2 = CsB;                               // slot 0: dense pooled adjacency
  float* slot1 = CsB + (size_t)NN*NN;             // slot 1: x buffers
  float* xs[4]; for(int i=0;i<4;i++) xs[i]=slot1+(size_t)i*NN*FF;
  float* xcur=slot1+(size_t)4*NN*FF;
  float* ybuf=slot1+(size_t)5*NN*FF;
  float* tbuf=slot1+(size_t)6*NN*FF;
  float* slot2 = CsB + 2ull*NN*NN;                // slot 2
  float* xcat=slot2;
  float* t16 = xcat + (size_t)NN*512;

  // workspace
  char* w=(char*)d_ws; size_t off=0;
  auto alc=[&](size_t b)->void*{ off=(off+255)&~(size_t)255; void* r=w+off; off+=b; return r; };
  Scal* sc=(Scal*)alc(sizeof(Scal));
  int* rowcnt=(int*)alc((size_t)NN*4);
  int* rp[4]; for(int i=0;i<4;i++) rp[i]=(int*)alc((size_t)(NN+1)*4);
  int* rp2=(int*)alc((size_t)(NN+1)*4);
  int* colsA[4]; float* acv[4];
  for(int i=0;i<4;i++){ colsA[i]=(int*)alc((size_t)CAPE*4); acv[i]=(float*)alc((size_t)CAPE*4); }
  float* avalS=(float*)alc((size_t)CAPE*4);
  float* cand=(float*)alc((size_t)CAPE*4);
  int* rows2=(int*)alc((size_t)CAPE*4);
  int* cols2=(int*)alc((size_t)CAPE*4);
  float* pval=(float*)alc((size_t)CAPE*4);
  unsigned* bins=(unsigned*)alc((size_t)65536*4);
  int* lab=(int*)alc((size_t)NN*4);
  int* nxt=(int*)alc((size_t)NN*4);
  int* labsv=(int*)alc((size_t)3*NN*4);
  int* clc=(int*)alc((size_t)NN*4);
  float* cntf=(float*)alc((size_t)NN*4);
  float* s1=(float*)alc((size_t)NN*4);
  float* s2v=(float*)alc((size_t)NN*4);
  float* Dv=(float*)alc((size_t)NN*4);

  auto build_csr=[&](const float* Ad, const float* ACd, const float* Dp, int lvl){
    k_count_dense<<<NN,256,0,stream>>>(Ad,rowcnt);
    k_scan<<<1,1024,0,stream>>>(rowcnt,rp[lvl],&sc->nnzS);
    k_fill_dense<<<NN,256,0,stream>>>(Ad,ACd,Dp,rp[lvl],colsA[lvl],avalS,acv[lvl]);
  };

  // level-0 CSR from inputs
  build_csr(adj,adjC,nullptr,0);

  // ---------- encode ----------
  for(int k=0;k<3;k++){
    const float* xin=(k==0)?x_in:xcur;
    const float* Wk=(k==0)?encW0:(encW+(size_t)(k-1)*FF*FF);
    const float* bk=(k==0)?encb0:(encb+(size_t)(k-1)*FF);
    int K=(k==0)?512:FF;
    k_gemm<<<dim3(FF/64,NN/64),256,0,stream>>>(xin,Wk,tbuf,NN,K,FF);
    k_spmm_gcn<<<NN/4,256,0,stream>>>(rp[k],colsA[k],acv[k],tbuf,bk,(k==0)?nullptr:xcur,xs[k],0);

    k_edge<<<NN,64,0,stream>>>(xs[k],fcW+(size_t)k*FF*64,fcb+(size_t)k*64,aW+(size_t)k*128,s1,s2v);
    hipMemsetAsync(attB+(size_t)k*NN*NN,0,(size_t)NN*NN*4,stream);
    k_snz<<<1,1,0,stream>>>(sc);
    k_att_fill<<<NN,256,0,stream>>>(rp[k],colsA[k],s1,s2v,attB+(size_t)k*NN*NN,cand,sc);

    // percentile
    k_prep<<<1,1,0,stream>>>(sc);
    hipMemsetAsync(bins,0,(size_t)65536*4,stream);
    k_hist<<<256,256,0,stream>>>(cand,sc,bins,0);
    k_pick<<<1,256,0,stream>>>(bins,sc,0);
    hipMemsetAsync(bins,0,(size_t)65536*4,stream);
    k_hist<<<256,256,0,stream>>>(cand,sc,bins,1);
    k_pick<<<1,256,0,stream>>>(bins,sc,1);
    k_minabove<<<256,256,0,stream>>>(cand,sc);
    k_cut<<<1,1,0,stream>>>(sc);

    // post-cut CSR
    k_pc_count<<<NN/4,256,0,stream>>>(rp[k],cand,sc,rowcnt,cntf);
    k_scan<<<1,1024,0,stream>>>(rowcnt,rp2,&sc->nnz2);
    k_pc_fill<<<NN/4,256,0,stream>>>(rp[k],colsA[k],cand,sc,rp2,rows2,cols2,pval,cntf);

    // connected components (min-label relax + pointer jump; unique fixed point)
    k_lab_init<<<NN/256,256,0,stream>>>(lab);
    int* cur=lab; int* oth=nxt;
    for(int p=0;p<8;p++){
      k_relax<<<CAPE/256,256,0,stream>>>(rows2,cols2,sc,cur);
      k_jump<<<NN/256,256,0,stream>>>(cur,oth);
      int* tmp=cur; cur=oth; oth=tmp;
    }
    hipMemsetAsync(clc,0,(size_t)NN*4,stream);
    k_labfin<<<NN/256,256,0,stream>>>(cur,labsv+(size_t)k*NN,clc);

    // a2 = C adj C^T (integer-exact atomics)
    hipMemsetAsync(dA2,0,(size_t)NN*NN*4,stream);
    k_a2<<<NN,256,0,stream>>>(rp[k],colsA[k],avalS,labsv+(size_t)k*NN,dA2);
    k_rowsumD<<<NN,256,0,stream>>>(dA2,Dv);

    // x2 = C ((att/cnt) x), then l2norm
    k_spmm_plain<<<NN/4,256,0,stream>>>(rp2,cols2,pval,xs[k],ybuf);
    k_x2norm<<<NN,256,0,stream>>>(ybuf,labsv+(size_t)k*NN,clc,xcur);

    // next-level CSR (aval consumed above; safe to overwrite)
    build_csr(dA2,nullptr,Dv,k+1);
  }

  // ---------- bottleneck ----------
  k_gemm<<<dim3(FF/64,NN/64),256,0,stream>>>(xcur,encW+(size_t)2*FF*FF,tbuf,NN,FF,FF);
  k_spmm_gcn<<<NN/4,256,0,stream>>>(rp[3],colsA[3],acv[3],tbuf,encb+(size_t)2*FF,nullptr,xs[3],1);

  // ---------- decode ----------
  float* xd=xs[3];
  float* outsb[3]={xcur,ybuf,xcur};
  for(int k=0;k<3;k++){
    int lev=2-k;
    k_gather<<<(NN*128)/256,256,0,stream>>>(xd,labsv+(size_t)lev*NN,xs[lev],xcat);
    k_gemm<<<dim3(FF/64,NN/64),256,0,stream>>>(xcat,decW+(size_t)k*512*FF,tbuf,NN,512,FF);
    k_spmm_gcn<<<NN/4,256,0,stream>>>(rp[lev],colsA[lev],acv[lev],tbuf,decb+(size_t)k*FF,nullptr,outsb[k],1);
    xd=outsb[k];
  }

  // ---------- final gcn + log_softmax ----------
  k_gemm16<<<(NN*16)/256,256,0,stream>>>(xd,decWo,t16);
  k_final<<<(NN+255)/256,256,0,stream>>>(rp[0],colsA[0],acv[0],t16,decbo,logp);

  // ---------- materialize Cs (wipes d_out scratch) ----------
  hipMemsetAsync(CsB,0,3ull*NN*NN*4,stream);
  k_cfill<<<(3*NN+255)/256,256,0,stream>>>(labsv,CsB);
}